// Round 10
// baseline (343.068 us; speedup 1.0000x reference)
//
#include <hip/hip_runtime.h>

// Problem constants
#define B 8
#define T 768
#define D 1024
#define H 16
#define DH 64
#define M (B*T)      // 6144
#define N3 (3*D)     // 3072
#define KDIM D       // 1024
#define QKV_ELEMS (B*H*T*DH)  // 6291456 elems per tensor
#define XE ((size_t)M * KDIM)    // 6291456
#define WE ((size_t)N3 * KDIM)   // 3145728

typedef __attribute__((ext_vector_type(8))) short bf16x8;
typedef __attribute__((ext_vector_type(4))) short bf16x4;
typedef __attribute__((ext_vector_type(4))) float f32x4;

__device__ __forceinline__ unsigned short f2bf(float x) {
    union { float f; unsigned u; } a; a.f = x;
    unsigned r = a.u + 0x7FFFu + ((a.u >> 16) & 1u);
    return (unsigned short)(r >> 16);
}
__device__ __forceinline__ float bf2f(unsigned short h) {
    union { unsigned u; float f; } a; a.u = ((unsigned)h) << 16;
    return a.f;
}

// async global->LDS, 16B per lane; LDS dest is wave-uniform base (HW adds lane*16)
__device__ __forceinline__ void gload_lds16(const void* g, void* l) {
    __builtin_amdgcn_global_load_lds(
        (const __attribute__((address_space(1))) void*)g,
        (__attribute__((address_space(3))) void*)l, 16, 0, 0);
}

// ---------------- Kernel 1: RoPE tables ----------------
__global__ void rope_tables_kernel(float* __restrict__ cosT, float* __restrict__ sinT) {
    int idx = blockIdx.x * blockDim.x + threadIdx.x;  // t*32 + i
    if (idx >= T * 32) return;
    int t = idx >> 5;
    int i = idx & 31;
    float inv_freq = powf(10000.0f, -(float)(2 * i) / 64.0f);
    float ang = (float)t * inv_freq;
    cosT[idx] = cosf(ang);
    sinT[idx] = sinf(ang);
}

// ---------------- Kernel 1b: fp32 -> bf16 hi/lo split (offline, once) ----------------
__global__ __launch_bounds__(256) void split_convert_kernel(
    const float* __restrict__ src, unsigned short* __restrict__ hi,
    unsigned short* __restrict__ lo, int n8)
{
    int i = blockIdx.x * blockDim.x + threadIdx.x;
    if (i >= n8) return;
    const float* p = src + (size_t)i * 8;
    float v[8];
    *(float4*)&v[0] = ((const float4*)p)[0];
    *(float4*)&v[4] = ((const float4*)p)[1];
    union { unsigned short u[8]; uint4 q; } hu, lu;
#pragma unroll
    for (int e = 0; e < 8; ++e) {
        unsigned short h = f2bf(v[e]);
        hu.u[e] = h;
        lu.u[e] = f2bf(v[e] - bf2f(h));
    }
    ((uint4*)hi)[i] = hu.q;
    ((uint4*)lo)[i] = lu.q;
}

#define BMq 128
#define BNq 128
#define BKq 32

// ---------------- Kernel 2: QKV GEMM (r8-verified structure), epilogue emits bf16 hi/lo ----------------
__global__ __launch_bounds__(256) void qkv_mfma2_kernel(
    const unsigned short* __restrict__ Xhi, const unsigned short* __restrict__ Xlo,
    const unsigned short* __restrict__ Whi, const unsigned short* __restrict__ Wlo,
    const float* __restrict__ bias, const float* __restrict__ cosT,
    const float* __restrict__ sinT,
    unsigned short* __restrict__ qhi, unsigned short* __restrict__ qlo,
    unsigned short* __restrict__ khi, unsigned short* __restrict__ klo,
    unsigned short* __restrict__ vhi, unsigned short* __restrict__ vlo)
{
    __shared__ unsigned short Ah[BMq * BKq], Al[BMq * BKq];
    __shared__ unsigned short Bh[BNq * BKq], Bl[BNq * BKq];   // 32 KB total

    const int tid  = threadIdx.x;
    const int lane = tid & 63;
    const int w    = tid >> 6;      // wave 0..3
    const int wr   = w >> 1;        // wave row 0..1
    const int wc   = w & 1;         // wave col 0..1
    const int lr   = lane & 15;
    const int kc   = lane >> 4;     // k-quarter 0..3

    const int m0 = blockIdx.x * BMq;
    const int n0 = blockIdx.y * BNq;

    f32x4 acc[4][4];
#pragma unroll
    for (int m = 0; m < 4; ++m)
#pragma unroll
        for (int n = 0; n < 4; ++n) acc[m][n] = (f32x4){0.f, 0.f, 0.f, 0.f};

    for (int k0 = 0; k0 < KDIM; k0 += BKq) {
        __syncthreads();
        // ---- stage 4 tiles of 8KB via global_load_lds ----
#pragma unroll
        for (int i = 0; i < 2; ++i) {
            int c   = w * 128 + i * 64 + lane;              // 16B-chunk index 0..511
            int row = c >> 2;
            int qq  = (c & 3) ^ ((row >> 1) & 3);           // pre-swizzled source quarter
            size_t goffA = (size_t)(m0 + row) * KDIM + k0 + qq * 8;
            size_t goffB = (size_t)(n0 + row) * KDIM + k0 + qq * 8;
            int lbase = (w * 128 + i * 64) * 8;             // wave-uniform LDS base (ushort idx)
            gload_lds16(Xhi + goffA, &Ah[lbase]);
            gload_lds16(Xlo + goffA, &Al[lbase]);
            gload_lds16(Whi + goffB, &Bh[lbase]);
            gload_lds16(Wlo + goffB, &Bl[lbase]);
        }
        __syncthreads();   // compiler drains vmcnt before barrier

        // ---- fragment loads (swizzled) ----
        bf16x8 ah[4], al[4], bh[4], bl[4];
#pragma unroll
        for (int m = 0; m < 4; ++m) {
            int r = wr * 64 + m * 16 + lr;
            int idx = r * 32 + (kc ^ ((r >> 1) & 3)) * 8;
            ah[m] = *(const bf16x8*)&Ah[idx];
            al[m] = *(const bf16x8*)&Al[idx];
        }
#pragma unroll
        for (int n = 0; n < 4; ++n) {
            int ccol = wc * 64 + n * 16 + lr;
            int idx = ccol * 32 + (kc ^ ((ccol >> 1) & 3)) * 8;
            bh[n] = *(const bf16x8*)&Bh[idx];
            bl[n] = *(const bf16x8*)&Bl[idx];
        }

        // ---- MFMA: hi*hi + hi*lo + lo*hi ----
#pragma unroll
        for (int m = 0; m < 4; ++m)
#pragma unroll
            for (int n = 0; n < 4; ++n) {
                acc[m][n] = __builtin_amdgcn_mfma_f32_16x16x32_bf16(ah[m], bh[n], acc[m][n], 0, 0, 0);
                acc[m][n] = __builtin_amdgcn_mfma_f32_16x16x32_bf16(ah[m], bl[n], acc[m][n], 0, 0, 0);
                acc[m][n] = __builtin_amdgcn_mfma_f32_16x16x32_bf16(al[m], bh[n], acc[m][n], 0, 0, 0);
            }
    }

    // ---- epilogue: bias + RoPE, split to bf16 hi/lo, scatter to (B,H,T,DH) ----
    const int section = n0 >> 10;                       // 0=q,1=k,2=v
    unsigned short* dhi = (section == 0) ? qhi : (section == 1) ? khi : vhi;
    unsigned short* dlo = (section == 0) ? qlo : (section == 1) ? klo : vlo;
    const int hcol = ((n0 & 1023) >> 6) + wc;           // head index

    float biasv[2][2];
#pragma unroll
    for (int np = 0; np < 2; ++np) {
        biasv[np][0] = bias[n0 + wc * 64 + np * 16 + lr];
        biasv[np][1] = bias[n0 + wc * 64 + np * 16 + lr + 32];
    }

#pragma unroll
    for (int m = 0; m < 4; ++m) {
#pragma unroll
        for (int j = 0; j < 4; ++j) {
            int grow = m0 + wr * 64 + m * 16 + (lane >> 4) * 4 + j;
            int bidx = grow / T;
            int t = grow - bidx * T;
            size_t rowbase = (((size_t)bidx * H + hcol) * T + t) * DH;
#pragma unroll
            for (int np = 0; np < 2; ++np) {
                int d = np * 16 + lr;                   // 0..31
                float vlo_ = acc[m][np][j]     + biasv[np][0];
                float vhi_ = acc[m][np + 2][j] + biasv[np][1];
                if (section < 2) {
                    float c = cosT[t * 32 + d];
                    float s = sinT[t * 32 + d];
                    float nl = vlo_ * c - vhi_ * s;
                    float nh = vhi_ * c + vlo_ * s;
                    vlo_ = nl; vhi_ = nh;
                }
                unsigned short h0 = f2bf(vlo_);
                dhi[rowbase + d]      = h0;
                dlo[rowbase + d]      = f2bf(vlo_ - bf2f(h0));
                unsigned short h1 = f2bf(vhi_);
                dhi[rowbase + d + 32] = h1;
                dlo[rowbase + d + 32] = f2bf(vhi_ - bf2f(h1));
            }
        }
    }
}

// ---------------- Kernel 3: retention, pre-split bf16 hi/lo inputs ----------------
// Block = 128 q-rows of one (b,h); 4 waves 2x2. Q frags direct-load (no convert).
// K staged via gload_lds16 into linear [64][64] with xor-8 chunk swizzle
// (source pre-swizzled, read same involution -> 2-way/free). V reg-staged
// transposed [d][s] (pure bf16 moves). S hi/lo through LDS as before.
#define SBLK 64
#define QBLK 128
#define LDK 72

__global__ __launch_bounds__(256) void retention_mfma_kernel(
    const unsigned short* __restrict__ qhi, const unsigned short* __restrict__ qlo,
    const unsigned short* __restrict__ khi, const unsigned short* __restrict__ klo,
    const unsigned short* __restrict__ vhi, const unsigned short* __restrict__ vlo,
    float* __restrict__ out)
{
    __shared__ unsigned short Kh[SBLK * DH], Kl[SBLK * DH];       // [s][d] linear, xor-8 swizzled
    __shared__ unsigned short Vth[DH * LDK], Vtl[DH * LDK];       // [d][s] transposed, padded
    __shared__ unsigned short Shi[QBLK * LDK], Slo[QBLK * LDK];   // [r][s]

    const int qb = blockIdx.x;       // 0..5
    const int bh = blockIdx.y;       // 0..127
    const int b = bh >> 4, h = bh & 15;
    const int tid = threadIdx.x;
    const int lane = tid & 63;
    const int w = tid >> 6;
    const int wm = w >> 1;           // q-half 0..1
    const int wc = w & 1;            // col-half 0..1
    const int lr = lane & 15;
    const int lg = lane >> 4;        // 0..3

    // ---- Q fragments: direct bf16 hi/lo loads (A-frag: row=lane&15, k=(lane>>4)*8+e) ----
    bf16x8 qh[4][2], ql[4][2];
    {
        const size_t qbase = ((size_t)bh * T + (size_t)qb * QBLK + wm * 64) * DH;
#pragma unroll
        for (int m = 0; m < 4; ++m)
#pragma unroll
            for (int kk = 0; kk < 2; ++kk) {
                size_t off = qbase + (size_t)(m * 16 + lr) * DH + kk * 32 + lg * 8;
                qh[m][kk] = *(const bf16x8*)(qhi + off);
                ql[m][kk] = *(const bf16x8*)(qlo + off);
            }
    }

    f32x4 oacc[4][2];
#pragma unroll
    for (int m = 0; m < 4; ++m)
#pragma unroll
        for (int n = 0; n < 2; ++n) oacc[m][n] = (f32x4){0.f, 0.f, 0.f, 0.f};

    const int qmin = qb * QBLK + wm * 64;
    const int niter = 2 * qb + 2;

    for (int sb = 0; sb < niter; ++sb) {
        __syncthreads();
        // ---- stage K via gload_lds16, xor-8 swizzled source ----
#pragma unroll
        for (int i = 0; i < 2; ++i) {
            int c    = w * 128 + i * 64 + lane;     // chunk 0..511 (8 chunks/row)
            int row  = c >> 3;                      // 0..63
            int slot = c & 7;
            int cg   = slot ^ (row & 7);            // inverse-swizzled global chunk
            size_t goff = ((size_t)bh * T + (size_t)sb * SBLK + row) * DH + cg * 8;
            int lbase = (w * 128 + i * 64) * 8;     // wave-uniform ushort base
            gload_lds16(khi + goff, &Kh[lbase]);
            gload_lds16(klo + goff, &Kl[lbase]);
        }
        // ---- stage V transposed [d][s] (pure bf16 moves) ----
        {
            int s0 = (tid >> 4) * 4, d0 = (tid & 15) * 4;
            size_t vbase = ((size_t)bh * T + (size_t)sb * SBLK + s0) * DH + d0;
            unsigned short rh[4][4], rl[4][4];
#pragma unroll
            for (int i = 0; i < 4; ++i) {
                *(bf16x4*)&rh[i][0] = *(const bf16x4*)(vhi + vbase + (size_t)i * DH);
                *(bf16x4*)&rl[i][0] = *(const bf16x4*)(vlo + vbase + (size_t)i * DH);
            }
#pragma unroll
            for (int j = 0; j < 4; ++j) {
                union { unsigned short u[4]; bf16x4 v4; } th, tl;
#pragma unroll
                for (int i = 0; i < 4; ++i) { th.u[i] = rh[i][j]; tl.u[i] = rl[i][j]; }
                int idx = (d0 + j) * LDK + s0;
                *(bf16x4*)&Vth[idx] = th.v4;
                *(bf16x4*)&Vtl[idx] = tl.v4;
            }
        }
        __syncthreads();

        const bool active = (sb * SBLK <= qmin + 63);
        if (active) {
            // ---- QK^T ----
            f32x4 sacc[4][2];
#pragma unroll
            for (int m = 0; m < 4; ++m)
#pragma unroll
                for (int n = 0; n < 2; ++n) sacc[m][n] = (f32x4){0.f, 0.f, 0.f, 0.f};

#pragma unroll
            for (int kk = 0; kk < 2; ++kk) {
                bf16x8 kbh[2], kbl[2];
#pragma unroll
                for (int n = 0; n < 2; ++n) {
                    int s = wc * 32 + n * 16 + lr;
                    int idx = s * 64 + ((kk * 4 + lg) ^ (s & 7)) * 8;   // matching swizzle
                    kbh[n] = *(const bf16x8*)&Kh[idx];
                    kbl[n] = *(const bf16x8*)&Kl[idx];
                }
#pragma unroll
                for (int m = 0; m < 4; ++m)
#pragma unroll
                    for (int n = 0; n < 2; ++n) {
                        sacc[m][n] = __builtin_amdgcn_mfma_f32_16x16x32_bf16(qh[m][kk], kbh[n], sacc[m][n], 0, 0, 0);
                        sacc[m][n] = __builtin_amdgcn_mfma_f32_16x16x32_bf16(qh[m][kk], kbl[n], sacc[m][n], 0, 0, 0);
                        sacc[m][n] = __builtin_amdgcn_mfma_f32_16x16x32_bf16(ql[m][kk], kbh[n], sacc[m][n], 0, 0, 0);
                    }
            }

            // ---- mask + split + write S to LDS ----
            const bool needmask = (sb * SBLK + 63 > qmin);
#pragma unroll
            for (int m = 0; m < 4; ++m)
#pragma unroll
                for (int n = 0; n < 2; ++n) {
                    int sl = wc * 32 + n * 16 + lr;
                    int sg = sb * SBLK + sl;
#pragma unroll
                    for (int j = 0; j < 4; ++j) {
                        int rl_ = wm * 64 + m * 16 + lg * 4 + j;
                        int rg = qb * QBLK + rl_;
                        float val = sacc[m][n][j];
                        if (needmask && sg > rg) val = 0.f;
                        unsigned short hv = f2bf(val);
                        int idx = rl_ * LDK + sl;
                        Shi[idx] = hv;
                        Slo[idx] = f2bf(val - bf2f(hv));
                    }
                }
        }
        __syncthreads();
        if (active) {
            // ---- PV: O += S @ V ----
#pragma unroll
            for (int kk = 0; kk < 2; ++kk) {
                bf16x8 vbh[2], vbl[2], sah[4], sal[4];
#pragma unroll
                for (int n = 0; n < 2; ++n) {
                    int d = wc * 32 + n * 16 + lr;
                    int idx = d * LDK + kk * 32 + lg * 8;
                    vbh[n] = *(const bf16x8*)&Vth[idx];
                    vbl[n] = *(const bf16x8*)&Vtl[idx];
                }
#pragma unroll
                for (int m = 0; m < 4; ++m) {
                    int r = wm * 64 + m * 16 + lr;
                    int idx = r * LDK + kk * 32 + lg * 8;
                    sah[m] = *(const bf16x8*)&Shi[idx];
                    sal[m] = *(const bf16x8*)&Slo[idx];
                }
#pragma unroll
                for (int m = 0; m < 4; ++m)
#pragma unroll
                    for (int n = 0; n < 2; ++n) {
                        oacc[m][n] = __builtin_amdgcn_mfma_f32_16x16x32_bf16(sah[m], vbh[n], oacc[m][n], 0, 0, 0);
                        oacc[m][n] = __builtin_amdgcn_mfma_f32_16x16x32_bf16(sah[m], vbl[n], oacc[m][n], 0, 0, 0);
                        oacc[m][n] = __builtin_amdgcn_mfma_f32_16x16x32_bf16(sal[m], vbh[n], oacc[m][n], 0, 0, 0);
                    }
            }
        }
    }

    // ---- epilogue: out[b][t][h*64 + d] ----
#pragma unroll
    for (int m = 0; m < 4; ++m)
#pragma unroll
        for (int n = 0; n < 2; ++n) {
            int dcol = wc * 32 + n * 16 + lr;
#pragma unroll
            for (int j = 0; j < 4; ++j) {
                int t = qb * QBLK + wm * 64 + m * 16 + lg * 4 + j;
                out[((size_t)b * T + t) * D + h * DH + dcol] = oacc[m][n][j];
            }
        }
}

// ---------------- launch ----------------
extern "C" void kernel_launch(void* const* d_in, const int* in_sizes, int n_in,
                              void* d_out, int out_size, void* d_ws, size_t ws_size,
                              hipStream_t stream) {
    const float* x    = (const float*)d_in[0];
    const float* Wq   = (const float*)d_in[1];
    const float* bq   = (const float*)d_in[2];
    float* out = (float*)d_out;

    // ws layout: 6 bf16 q/k/v hi/lo arrays, cos/sin tables, X/W split arrays
    unsigned short* qhi = (unsigned short*)d_ws;
    unsigned short* qlo = qhi + QKV_ELEMS;
    unsigned short* khi = qlo + QKV_ELEMS;
    unsigned short* klo = khi + QKV_ELEMS;
    unsigned short* vhi = klo + QKV_ELEMS;
    unsigned short* vlo = vhi + QKV_ELEMS;
    float* cosT = (float*)(vlo + QKV_ELEMS);
    float* sinT = cosT + T * 32;
    unsigned short* Xhi = (unsigned short*)(sinT + T * 32);
    unsigned short* Xlo = Xhi + XE;
    unsigned short* Whi = Xlo + XE;
    unsigned short* Wlo = Whi + WE;

    rope_tables_kernel<<<dim3((T * 32 + 255) / 256), dim3(256), 0, stream>>>(cosT, sinT);
    split_convert_kernel<<<dim3((int)(XE / 8 / 256)), dim3(256), 0, stream>>>(x,  Xhi, Xlo, (int)(XE / 8));
    split_convert_kernel<<<dim3((int)(WE / 8 / 256)), dim3(256), 0, stream>>>(Wq, Whi, Wlo, (int)(WE / 8));
    qkv_mfma2_kernel<<<dim3(M / BMq, N3 / BNq), dim3(256), 0, stream>>>(
        Xhi, Xlo, Whi, Wlo, bq, cosT, sinT, qhi, qlo, khi, klo, vhi, vlo);
    retention_mfma_kernel<<<dim3(T / QBLK, B * H), dim3(256), 0, stream>>>(
        qhi, qlo, khi, klo, vhi, vlo, out);
}